// Round 1
// 436.660 us; speedup vs baseline: 1.0613x; 1.0613x over previous
//
#include <hip/hip_runtime.h>
#include <stdint.h>

#define B_ROWS 8192
#define DIM 4096
#define E_CODES 512
#define MARGIN 16.0f

typedef __attribute__((ext_vector_type(8))) short short8;
typedef __attribute__((ext_vector_type(4))) float floatx4;
typedef __attribute__((ext_vector_type(4), aligned(4))) float f4u;  // unaligned-ok float4
typedef unsigned short ushort_t;

// ---- workspace layout (float units) ---- (unchanged size vs previous version)
#define WS_P0     0                       // partial scores half 0: 8192*512 floats
#define WS_ENORM  4194304                 // 512 floats
#define WS_COUNTS 4194816                 // 512 ints
#define WS_LOSS   4195328                 // 1 float (contiguous after counts)

// ---- output layout (float units) ----
#define O_LOSS 0
#define O_Q    1
#define O_PERP 33554433
#define O_ENC  33554434
// scratch carved out of the Q region (Q is fully overwritten by k_fused afterwards):
#define O_XBF  4          // bf16 X (swizzled): 8192*4096 ushort -> floats [4, 16777220)
#define O_CBBF 20971520   // bf16 CB (swizzled): 512*4096 ushort -> floats [20971520, 22020096)
// partial scores half 1 lives in the ENC region (read before k_fused overwrites it per-row)

#define AS1 __attribute__((address_space(1)))
#define AS3 __attribute__((address_space(3)))

__device__ __forceinline__ void gld_lds16(const void* g, void* l) {
    // async global->LDS, 16B per lane; LDS dest = wave-uniform base + lane*16
    __builtin_amdgcn_global_load_lds((AS1 const void*)g, (AS3 void*)l, 16, 0, 0);
}

// pack two fp32 into (bf16(hi)<<16)|bf16(lo) by truncation — one v_perm_b32
__device__ inline uint32_t pk2(float hi, float lo) {
    return __builtin_amdgcn_perm(__float_as_uint(hi), __float_as_uint(lo), 0x07060302u);
}

// ---------------- codebook norms (fp32) ----------------
__global__ __launch_bounds__(64) void k_enorm(const float* __restrict__ cb, float* __restrict__ enorm) {
    const int e = blockIdx.x;
    const int lane = threadIdx.x;
    const float4* c4 = (const float4*)(cb + (size_t)e * DIM);
    float p = 0.f;
#pragma unroll
    for (int j = 0; j < 16; j++) {
        float4 v = c4[j * 64 + lane];
        p = fmaf(v.x, v.x, fmaf(v.y, v.y, fmaf(v.z, v.z, fmaf(v.w, v.w, p))));
    }
    for (int off = 32; off; off >>= 1) p += __shfl_down(p, off);
    if (lane == 0) enorm[e] = p;
}

// ---------------- bf16 pack with per-row XOR swizzle ----------------
// Within each 64-element K-block, 16B-chunk c is stored at chunk (c ^ (row&7)).
// global_load_lds then stages linearly and the GEMM frag ds_read applies the same
// XOR -> conflict-free ds_read_b128 (rule #21: swz source + linear dest + swz read).
#define GX_CH (B_ROWS * (DIM / 8))    // 4,194,304 chunks of 8 floats
#define GC_CH (E_CODES * (DIM / 8))   // 262,144
__global__ __launch_bounds__(256) void k_pack(const float* __restrict__ X, const float* __restrict__ CB,
                                              ushort_t* __restrict__ xbf, ushort_t* __restrict__ cbbf) {
    const int stride = gridDim.x * 256;
    for (int idx = blockIdx.x * 256 + threadIdx.x; idx < GX_CH + GC_CH; idx += stride) {
        const float* s;
        ushort_t* dbase;
        int r, g;
        if (idx < GX_CH) {
            r = idx >> 9; g = idx & 511;
            s = X + ((size_t)idx << 3);
            dbase = xbf + (size_t)r * DIM;
        } else {
            const int t = idx - GX_CH;
            r = t >> 9; g = t & 511;
            s = CB + ((size_t)t << 3);
            dbase = cbbf + (size_t)r * DIM;
        }
        const int gs = (g & ~7) | ((g & 7) ^ (r & 7));
        const float4* s4 = (const float4*)s;
        float4 v0 = s4[0], v1 = s4[1];
        *(uint4*)(dbase + gs * 8) =
            make_uint4(pk2(v0.y, v0.x), pk2(v0.w, v0.z), pk2(v1.y, v1.x), pk2(v1.w, v1.z));
    }
}

// ---------------- bf16 score GEMM, m97 structure ----------------
// 128x128 tile, BK=64, 256 threads = 4 waves (2x2), each wave 64x64 out (4x4 frags of 16x16x32).
// Split-K=2: grid = 64 bm * 4 bn * 2 kh = 512 blocks -> 2 blocks/CU, 8 waves/CU.
// Staging: 8x global_load_lds dwordx4 per thread per K-step, single LDS buffer, 2 barriers/step.
__global__ __launch_bounds__(256, 2) void k_gemm(const ushort_t* __restrict__ xbf, const ushort_t* __restrict__ cbbf,
                                                 const float* __restrict__ enorm,
                                                 float* __restrict__ p0, float* __restrict__ p1) {
    __shared__ __align__(16) ushort_t As[128 * 64];
    __shared__ __align__(16) ushort_t Bs[128 * 64];
    const int bid = blockIdx.x;
    const int kh = bid & 1;
    const int bn = (bid >> 1) & 3;
    const int bm = bid >> 3;
    const int tid = threadIdx.x;
    const int lane = tid & 63;
    const int w = tid >> 6;
    const int wr = w >> 1, wc = w & 1;
    const int m16 = lane & 15, q4 = lane >> 4;

    // staging: chunk (j*4+w) covers LDS rows chunk*8..chunk*8+7; lane -> (row lane>>3, col (lane&7)*8)
    const int srow = lane >> 3;
    const int scol = (lane & 7) * 8;
    const ushort_t* ax = xbf + (size_t)(bm * 128 + w * 8 + srow) * DIM + kh * 2048 + scol;
    const ushort_t* bx = cbbf + (size_t)(bn * 128 + w * 8 + srow) * DIM + kh * 2048 + scol;
    ushort_t* asd = &As[w * 512];   // + j*2048 per load
    ushort_t* bsd = &Bs[w * 512];

    floatx4 acc[4][4];
#pragma unroll
    for (int i = 0; i < 4; i++)
#pragma unroll
        for (int j = 0; j < 4; j++) acc[i][j] = (floatx4){0.f, 0.f, 0.f, 0.f};

    const int kx = (m16 & 7) * 8;  // frag-read XOR key (ushort units) == byte>>1 of ((row&7)<<4)

    for (int kt = 0; kt < 2048; kt += 64) {
        __syncthreads();  // all waves done reading LDS from previous step
#pragma unroll
        for (int j = 0; j < 4; j++) gld_lds16(ax + (size_t)j * 32 * DIM + kt, asd + j * 2048);
#pragma unroll
        for (int j = 0; j < 4; j++) gld_lds16(bx + (size_t)j * 32 * DIM + kt, bsd + j * 2048);
        asm volatile("s_waitcnt vmcnt(0)" ::: "memory");
        __syncthreads();  // staged tile visible to all waves

        short8 a[4][2], b[4][2];
#pragma unroll
        for (int i = 0; i < 4; i++)
#pragma unroll
            for (int kk = 0; kk < 2; kk++) {
                a[i][kk] = *(const short8*)(&As[(wr * 64 + i * 16 + m16) * 64 + ((kk * 32 + q4 * 8) ^ kx)]);
                b[i][kk] = *(const short8*)(&Bs[(wc * 64 + i * 16 + m16) * 64 + ((kk * 32 + q4 * 8) ^ kx)]);
            }
#pragma unroll
        for (int kk = 0; kk < 2; kk++)
#pragma unroll
            for (int i = 0; i < 4; i++)
#pragma unroll
                for (int j = 0; j < 4; j++)
                    acc[i][j] = __builtin_amdgcn_mfma_f32_16x16x32_bf16(a[i][kk], b[j][kk], acc[i][j], 0, 0, 0);
    }

    // epilogue: P0 = ||e||^2 - 2*dot_lo ; P1 = -2*dot_hi ; C/D layout col=lane&15, row=(lane>>4)*4+rr
    float* P = kh ? p1 : p0;
#pragma unroll
    for (int j = 0; j < 4; j++) {
        const int col = bn * 128 + wc * 64 + j * 16 + m16;
        const float en = kh ? 0.f : enorm[col];
#pragma unroll
        for (int i = 0; i < 4; i++) {
            const int row0 = bm * 128 + wr * 64 + i * 16 + q4 * 4;
#pragma unroll
            for (int rr = 0; rr < 4; rr++)
                P[(size_t)(row0 + rr) * E_CODES + col] = fmaf(-2.0f, acc[i][j][rr], en);
        }
    }
}

// ---------------- fused: wave-per-row argmin + exact refine + quantize + one-hot + loss ----------------
// p1 aliases the one-hot output region (each wave reads its own row fully before writing it);
// no __restrict__ on p1/out.
__global__ __launch_bounds__(256) void k_fused(const float* __restrict__ X, const float* __restrict__ CB,
                                               const float* __restrict__ p0, const float* p1,
                                               int* __restrict__ counts, float* __restrict__ loss_sum,
                                               float* out) {
    const int tid = threadIdx.x;
    const int lane = tid & 63, w = tid >> 6;
    const int row = blockIdx.x * 4 + w;

    const float* sr0 = p0 + (size_t)row * E_CODES;
    const float* sr1 = p1 + (size_t)row * E_CODES;
    float s[8];
#pragma unroll
    for (int g = 0; g < 8; g++) s[g] = sr0[g * 64 + lane] + sr1[g * 64 + lane];

    // wave argmin (approx scores), tie -> lower index
    float mv = s[0]; int mi = lane;
#pragma unroll
    for (int g = 1; g < 8; g++) { if (s[g] < mv) { mv = s[g]; mi = g * 64 + lane; } }
    for (int off = 32; off; off >>= 1) {
        float ov = __shfl_xor(mv, off); int oi = __shfl_xor(mi, off);
        if (ov < mv || (ov == mv && oi < mi)) { mv = ov; mi = oi; }
    }
    const float thr = mv + MARGIN;

    // X row resident in registers
    const float4* xr4 = (const float4*)(X + (size_t)row * DIM);
    float4 xv[16];
#pragma unroll
    for (int i = 0; i < 16; i++) xv[i] = xr4[i * 64 + lane];

    // exact fp32 evaluation of margin candidates; butterfly sums are bit-identical on all lanes
    float bestd = 3.0e38f; int beste = 1 << 30;
#pragma unroll 1
    for (int g = 0; g < 8; g++) {
        unsigned long long mask = __ballot(s[g] <= thr);
        while (mask) {
            const int b = __builtin_ctzll(mask); mask &= mask - 1;
            const int e = g * 64 + b;
            const float4* cr4 = (const float4*)(CB + (size_t)e * DIM);
            float p = 0.f;
#pragma unroll
            for (int i = 0; i < 16; i++) {
                float4 c = cr4[i * 64 + lane];
                float dx = xv[i].x - c.x, dy = xv[i].y - c.y, dz = xv[i].z - c.z, dw = xv[i].w - c.w;
                p = fmaf(dx, dx, fmaf(dy, dy, fmaf(dz, dz, fmaf(dw, dw, p))));
            }
            for (int off = 32; off; off >>= 1) p += __shfl_xor(p, off);
            if (p < bestd || (p == bestd && e < beste)) { bestd = p; beste = e; }
        }
    }

    // quantized_st = x + (q - x), fp32 semantics of the reference
    const float4* cq4 = (const float4*)(CB + (size_t)beste * DIM);
    f4u* oq4 = (f4u*)(out + O_Q + (size_t)row * DIM);   // out+1 is only 4B-aligned
#pragma unroll
    for (int i = 0; i < 16; i++) {
        float4 x = xv[i], q = cq4[i * 64 + lane];
        f4u r;
        r.x = x.x + (q.x - x.x); r.y = x.y + (q.y - x.y);
        r.z = x.z + (q.z - x.z); r.w = x.w + (q.w - x.w);
        oq4[i * 64 + lane] = r;
    }

    // one-hot row (O_ENC is 8B-aligned -> float2); overwrites the p1 row we already consumed
    float2* oe2 = (float2*)(out + O_ENC + (size_t)row * E_CODES);
#pragma unroll
    for (int k = 0; k < 4; k++) {
        const int e0 = (k * 64 + lane) * 2;
        float2 v; v.x = (e0 == beste) ? 1.0f : 0.0f; v.y = (e0 + 1 == beste) ? 1.0f : 0.0f;
        oe2[k * 64 + lane] = v;
    }

    if (lane == 0) {
        atomicAdd(&counts[beste], 1);
        atomicAdd(loss_sum, bestd);      // bestd == sum((q-x)^2), exact fp32
    }
}

// ---------------- loss + perplexity ----------------
__global__ __launch_bounds__(512) void k_final(const int* __restrict__ counts, const float* __restrict__ loss_sum,
                                               float* __restrict__ out) {
    const int tid = threadIdx.x;
    const int lane = tid & 63, w = tid >> 6;
    __shared__ float r[8];
    const float p = (float)counts[tid] * (1.0f / 8192.0f);
    float h = p * logf(p + 1e-10f);
    for (int off = 32; off; off >>= 1) h += __shfl_down(h, off);
    if (lane == 0) r[w] = h;
    __syncthreads();
    if (tid == 0) {
        float H = 0.f;
        for (int k = 0; k < 8; k++) H += r[k];
        out[O_PERP] = expf(-H);
        out[O_LOSS] = loss_sum[0] * (1.25f / 33554432.0f);  // q_latent + 0.25*e_latent = 1.25*MSE
    }
}

extern "C" void kernel_launch(void* const* d_in, const int* in_sizes, int n_in,
                              void* d_out, int out_size, void* d_ws, size_t ws_size,
                              hipStream_t stream) {
    const float* X  = (const float*)d_in[0];   // inputs  [8192, 8,8,8,8] -> [8192,4096]
    const float* CB = (const float*)d_in[1];   // codebook [512, 4096]
    float* out = (float*)d_out;
    float* ws  = (float*)d_ws;
    float* p0     = ws + WS_P0;
    float* enorm  = ws + WS_ENORM;
    int*   counts = (int*)(ws + WS_COUNTS);
    float* loss_s = ws + WS_LOSS;
    ushort_t* xbf  = (ushort_t*)(out + O_XBF);
    ushort_t* cbbf = (ushort_t*)(out + O_CBBF);
    float* p1 = out + O_ENC;

    hipMemsetAsync(counts, 0, (E_CODES + 1) * sizeof(int), stream);

    k_pack<<<2048, 256, 0, stream>>>(X, CB, xbf, cbbf);
    k_enorm<<<E_CODES, 64, 0, stream>>>(CB, enorm);
    k_gemm<<<512, 256, 0, stream>>>(xbf, cbbf, enorm, p0, p1);
    k_fused<<<B_ROWS / 4, 256, 0, stream>>>(X, CB, p0, p1, counts, loss_s, out);
    k_final<<<1, 512, 0, stream>>>(counts, loss_s, out);
}